// Round 1
// baseline (248.711 us; speedup 1.0000x reference)
//
#include <hip/hip_runtime.h>
#include <hip/hip_bf16.h>

#define DIM 128
#define NN 40000
#define NE 640000
#define NBLK ((NN + 255) / 256)   // 157

// gfx950 bf16 MFMA fragment types (learn_hip m89/m93/m97):
typedef __attribute__((ext_vector_type(8))) short s16x8;   // 8 bf16 in 4 VGPRs
typedef __attribute__((ext_vector_type(4))) float f32x4;
typedef __attribute__((ext_vector_type(4))) unsigned short u16x4;
typedef __attribute__((ext_vector_type(4))) unsigned int u32x4;

__device__ __forceinline__ float bf16_lo(unsigned v) { return __uint_as_float(v << 16); }
__device__ __forceinline__ float bf16_hi(unsigned v) { return __uint_as_float(v & 0xffff0000u); }
__device__ __forceinline__ unsigned short f_to_bf16(float f) {
    unsigned u = __float_as_uint(f);
    u += 0x7fffu + ((u >> 16) & 1u);   // round-to-nearest-even
    return (unsigned short)(u >> 16);
}

__global__ void fill_const_f32(float* __restrict__ out, int n, float v) {
    int i = blockIdx.x * blockDim.x + threadIdx.x;
    if (i < n) out[i] = v;
}

// ---------------- fused: fp32->bf16 cvt (x + weights) + zero deg + fmt detect ----
// blocks 0..4999: x (4 elems/thread); 5000..5063: weights; 5064..5220: zero deg
// (+ block 5064 lanes 0..63 detect int64-vs-int32 edge_index).
__global__ void cvt_all(const float* __restrict__ x, unsigned short* __restrict__ xb,
                        const float* __restrict__ w0, const float* __restrict__ w1,
                        const float* __restrict__ w2, const float* __restrict__ w3,
                        unsigned short* __restrict__ wb,
                        int* __restrict__ deg, const int* __restrict__ ei,
                        int* __restrict__ flag) {
    int b = blockIdx.x;
    if (b >= 5064) {
        int i = (b - 5064) * 256 + threadIdx.x;
        if (i < NN) deg[i] = 0;
        if (b == 5064 && threadIdx.x < 64) {
            // int64 passthrough: odd words (high halves, values < 40000) all zero
            int w = ei[2 * threadIdx.x + 1];
            unsigned long long m = __ballot(w == 0);
            if (threadIdx.x == 0) *flag = (m == ~0ull) ? 1 : 0;   // 1 = int64
        }
        return;
    }
    const float* src;
    unsigned short* dst;
    size_t i;
    if (b < 5000) {
        src = x; dst = xb;
        i = (size_t)b * 256 + threadIdx.x;           // 1,280,000 f32x4 groups
    } else {
        int w = b - 5000;
        int m = w >> 4;                               // matrix 0..3
        src = (m == 0) ? w0 : (m == 1) ? w1 : (m == 2) ? w2 : w3;
        dst = wb + (size_t)m * 16384;
        i = (size_t)(w & 15) * 256 + threadIdx.x;     // 4096 groups per matrix
    }
    f32x4 v = *(const f32x4*)(src + 4 * i);
    u16x4 o;
    o.x = f_to_bf16(v.x); o.y = f_to_bf16(v.y);
    o.z = f_to_bf16(v.z); o.w = f_to_bf16(v.w);
    *(u16x4*)(dst + 4 * i) = o;
}

// ---------------- CSR build ----------------

__global__ void count_deg(const int* __restrict__ ei, const int* __restrict__ fmt,
                          int* __restrict__ deg) {
    int e = blockIdx.x * blockDim.x + threadIdx.x;
    if (e >= NE) return;
    int dst = (*fmt) ? ((const int2*)ei)[NE + e].x : ei[NE + e];
    if ((unsigned)dst < (unsigned)NN) atomicAdd(&deg[dst], 1);
}

__global__ void block_sums(const int* __restrict__ deg, int* __restrict__ bsum) {
    __shared__ int sh[256];
    int i = blockIdx.x * 256 + threadIdx.x;
    sh[threadIdx.x] = (i < NN) ? deg[i] : 0;
    __syncthreads();
    for (int off = 128; off > 0; off >>= 1) {
        if (threadIdx.x < off) sh[threadIdx.x] += sh[threadIdx.x + off];
        __syncthreads();
    }
    if (threadIdx.x == 0) bsum[blockIdx.x] = sh[0];
}

// merged scan: each block redundantly LDS-scans the 157 block sums (8 steps,
// no serial tail) to get its base, then local-scans its 256 deg entries.
__global__ void scan_block2(const int* __restrict__ deg, const int* __restrict__ bsum,
                            int* __restrict__ row_ptr, int* __restrict__ cursor) {
    __shared__ int sh[256];
    int t = threadIdx.x, bid = blockIdx.x;

    int v0 = (t < NBLK) ? bsum[t] : 0;
    sh[t] = v0;
    __syncthreads();
    for (int off = 1; off < 256; off <<= 1) {
        int u = (t >= off) ? sh[t - off] : 0;
        __syncthreads();
        sh[t] += u;
        __syncthreads();
    }
    int base = sh[bid] - bsum[bid];   // exclusive prefix of earlier chunks
    __syncthreads();

    int i = bid * 256 + t;
    int v = (i < NN) ? deg[i] : 0;
    sh[t] = v;
    __syncthreads();
    for (int off = 1; off < 256; off <<= 1) {
        int u = (t >= off) ? sh[t - off] : 0;
        __syncthreads();
        sh[t] += u;
        __syncthreads();
    }
    int excl = sh[t] - v + base;
    if (i < NN) { row_ptr[i] = excl; cursor[i] = excl; }
    if (i == NN - 1) row_ptr[NN] = excl + v;
}

__global__ void fill_csr(const int* __restrict__ ei, const int* __restrict__ fmt,
                         int* __restrict__ cursor, int* __restrict__ sorted_src) {
    int e = blockIdx.x * blockDim.x + threadIdx.x;
    if (e >= NE) return;
    int src, dst;
    if (*fmt) {
        src = ((const int2*)ei)[e].x;
        dst = ((const int2*)ei)[NE + e].x;
    } else {
        src = ei[e];
        dst = ei[NE + e];
    }
    if ((unsigned)dst >= (unsigned)NN) return;
    int pos = atomicAdd(&cursor[dst], 1);
    if ((unsigned)pos < (unsigned)NE) sorted_src[pos] = src;
}

// ---------------- mean aggregation: one 16-lane group per node ----------------
// 4 nodes per wave; each lane owns 16 B of its node's row. v2 (this round):
// batch-load 16 edge indices per group in ONE coalesced load (sorted_src[i+lid]),
// broadcast via __shfl, issue 16 independent gathers per batch (vs 4 before),
// dual accumulator chains to break the serial-add dependency. Remainder uses
// the same unrolled body under per-group predicates so its loads also issue
// back-to-back (old code: one dependent index load + gather per edge).

#define ACC8(A, v)                                 \
    A[0] += bf16_lo((v).x); A[1] += bf16_hi((v).x); \
    A[2] += bf16_lo((v).y); A[3] += bf16_hi((v).y); \
    A[4] += bf16_lo((v).z); A[5] += bf16_hi((v).z); \
    A[6] += bf16_lo((v).w); A[7] += bf16_hi((v).w);

__global__ __launch_bounds__(256) void aggregate_g(
    const unsigned short* __restrict__ xin,
    const int* __restrict__ row_ptr,
    const int* __restrict__ sorted_src,
    unsigned short* __restrict__ mean_out) {
    int lane = threadIdx.x & 63;
    int wv = threadIdx.x >> 6;
    int grp = lane >> 4;     // node within wave
    int lid = lane & 15;     // 16 B sub-chunk of the 256 B row
    int gbase = grp << 4;
    int n = blockIdx.x * 16 + wv * 4 + grp;
    int start = row_ptr[n], end = row_ptr[n + 1];

    float a[8] = {0.f, 0.f, 0.f, 0.f, 0.f, 0.f, 0.f, 0.f};
    float b[8] = {0.f, 0.f, 0.f, 0.f, 0.f, 0.f, 0.f, 0.f};

    int i = start;
    // full batches of 16 edges: 1 coalesced index load, 16 gathers in flight
    for (; i + 16 <= end; i += 16) {
        int idx = sorted_src[i + lid];
#pragma unroll
        for (int j = 0; j < 16; j += 4) {
            int s0 = __shfl(idx, gbase + j);
            int s1 = __shfl(idx, gbase + j + 1);
            int s2 = __shfl(idx, gbase + j + 2);
            int s3 = __shfl(idx, gbase + j + 3);
            u32x4 v0 = *(const u32x4*)(xin + (size_t)s0 * DIM + lid * 8);
            u32x4 v1 = *(const u32x4*)(xin + (size_t)s1 * DIM + lid * 8);
            u32x4 v2 = *(const u32x4*)(xin + (size_t)s2 * DIM + lid * 8);
            u32x4 v3 = *(const u32x4*)(xin + (size_t)s3 * DIM + lid * 8);
            ACC8(a, v0);
            ACC8(b, v1);
            ACC8(a, v2);
            ACC8(b, v3);
        }
    }
    // remainder (< 16 edges): same unrolled body, per-group predicated so all
    // remaining gathers still issue without per-edge latency chains
    int rem = end - i;
    if (rem > 0) {
        int src_i = (i + lid < end) ? (i + lid) : (end - 1);
        int idx = sorted_src[src_i];
#pragma unroll
        for (int j = 0; j < 16; ++j) {
            if (j < rem) {
                int s = __shfl(idx, gbase + j);
                u32x4 v = *(const u32x4*)(xin + (size_t)s * DIM + lid * 8);
                if (j & 1) { ACC8(b, v); }
                else       { ACC8(a, v); }
            }
        }
    }

#pragma unroll
    for (int k = 0; k < 8; ++k) a[k] += b[k];

    int d = end - start;
    float inv = 1.f / (float)(d > 1 ? d : 1);
    u32x4 o;
    o.x = (unsigned)f_to_bf16(a[0] * inv) | ((unsigned)f_to_bf16(a[1] * inv) << 16);
    o.y = (unsigned)f_to_bf16(a[2] * inv) | ((unsigned)f_to_bf16(a[3] * inv) << 16);
    o.z = (unsigned)f_to_bf16(a[4] * inv) | ((unsigned)f_to_bf16(a[5] * inv) << 16);
    o.w = (unsigned)f_to_bf16(a[6] * inv) | ((unsigned)f_to_bf16(a[7] * inv) << 16);
    *(u32x4*)(mean_out + (size_t)n * DIM + lid * 8) = o;
}

// ---------------- fused SAGE linear: relu(mean@Wl^T + b + h@Wr^T) (r11-proven) ----
// 64 rows x 16 cols per wave: 4 stacked 16x16 tiles, B-frags loaded once and
// reused 4x, A double-buffered. mfma_f32_16x16x32_bf16 layouts (m89/m120):
//   A: A[m=lane&15][k=quad*8+j]; B = W[col][k..k+7]; C/D: col=lane&15, row=quad*4+reg.

template <bool WRITE_F32>
__global__ __launch_bounds__(256) void sage_gemm(
    const unsigned short* __restrict__ mean,   // [N,128] bf16
    const unsigned short* __restrict__ hself,  // [N,128] bf16
    const unsigned short* __restrict__ Wl,     // [128,128] bf16
    const unsigned short* __restrict__ Wr,
    const float* __restrict__ bias,            // [128] fp32
    void* __restrict__ outv) {
    int lane = threadIdx.x & 63;
    int wv = threadIdx.x >> 6;
    int quad = lane >> 4;
    int lid = lane & 15;
    int row0 = blockIdx.x * 64;
    int bcol = blockIdx.y * 64 + wv * 16 + lid;

    const unsigned short* wl0 = Wl + (size_t)bcol * DIM + quad * 8;
    const unsigned short* wr0 = Wr + (size_t)bcol * DIM + quad * 8;
    s16x8 bl[4], br[4];
#pragma unroll
    for (int kb = 0; kb < 4; ++kb) {
        bl[kb] = *(const s16x8*)(wl0 + kb * 32);
        br[kb] = *(const s16x8*)(wr0 + kb * 32);
    }

    const unsigned short* ap = mean + (size_t)(row0 + lid) * DIM + quad * 8;
    const unsigned short* hp = hself + (size_t)(row0 + lid) * DIM + quad * 8;
    const int TS = 16 * DIM;

    f32x4 acc[4] = {{0,0,0,0},{0,0,0,0},{0,0,0,0},{0,0,0,0}};
    s16x8 am[2][4], ah[2][4];

#pragma unroll
    for (int kb = 0; kb < 4; ++kb) {
        am[0][kb] = *(const s16x8*)(ap + kb * 32);
        ah[0][kb] = *(const s16x8*)(hp + kb * 32);
    }
#pragma unroll
    for (int t = 0; t < 4; ++t) {
        int cb = t & 1, nb = (t + 1) & 1;
        if (t < 3) {
#pragma unroll
            for (int kb = 0; kb < 4; ++kb) {
                am[nb][kb] = *(const s16x8*)(ap + (t + 1) * TS + kb * 32);
                ah[nb][kb] = *(const s16x8*)(hp + (t + 1) * TS + kb * 32);
            }
        }
#pragma unroll
        for (int kb = 0; kb < 4; ++kb)
            acc[t] = __builtin_amdgcn_mfma_f32_16x16x32_bf16(am[cb][kb], bl[kb], acc[t], 0, 0, 0);
#pragma unroll
        for (int kb = 0; kb < 4; ++kb)
            acc[t] = __builtin_amdgcn_mfma_f32_16x16x32_bf16(ah[cb][kb], br[kb], acc[t], 0, 0, 0);
    }

    float bv = bias[bcol];
#pragma unroll
    for (int t = 0; t < 4; ++t) {
#pragma unroll
        for (int r = 0; r < 4; ++r) {
            int orow = row0 + t * 16 + quad * 4 + r;
            float v = fmaxf(acc[t][r] + bv, 0.f);   // relu
            if (WRITE_F32)
                ((float*)outv)[(size_t)orow * DIM + bcol] = v;
            else
                ((unsigned short*)outv)[(size_t)orow * DIM + bcol] = f_to_bf16(v);
        }
    }
}

// ---------------- launch ----------------

extern "C" void kernel_launch(void* const* d_in, const int* in_sizes, int n_in,
                              void* d_out, int out_size, void* d_ws, size_t ws_size,
                              hipStream_t stream) {
    const float* x   = (const float*)d_in[0];
    const int*   ei  = (const int*)d_in[1];
    const float* W1l = (const float*)d_in[2];
    const float* b1l = (const float*)d_in[3];
    const float* W1r = (const float*)d_in[4];
    const float* W2l = (const float*)d_in[5];
    const float* b2l = (const float*)d_in[6];
    const float* W2r = (const float*)d_in[7];
    float* out = (float*)d_out;

    const int OUT_ELEMS = NN * DIM;        // 5,120,000

    // workspace layout (256B-aligned)
    const size_t OFF_DEG  = 0;             // N ints
    const size_t OFF_ROW  = 163840;        // N+1 ints
    const size_t OFF_BSUM = 324608;        // NBLK ints (in ROW region slack)
    const size_t OFF_CUR  = 327680;        // N ints
    const size_t OFF_FMT  = 491264;        // 1 int
    const size_t OFF_SRT  = 491520;        // E ints
    const size_t OFF_WB   = 3051520;       // 4 * 16384 bf16
    const size_t OFF_XB   = 3182592;       // N*128 bf16
    const size_t OFF_MEAN = 13422592;      // N*128 bf16
    const size_t OFF_H1   = 23662592;      // N*128 bf16
    const size_t NEEDED   = 33902592;

    if (ws_size < NEEDED) {
        fill_const_f32<<<(OUT_ELEMS + 255) / 256, 256, 0, stream>>>(out, OUT_ELEMS, 50.0f);
        return;
    }

    char* ws = (char*)d_ws;
    int* deg     = (int*)(ws + OFF_DEG);
    int* row_ptr = (int*)(ws + OFF_ROW);
    int* bsum    = (int*)(ws + OFF_BSUM);
    int* cursor  = (int*)(ws + OFF_CUR);
    int* fmtflag = (int*)(ws + OFF_FMT);
    int* sorted  = (int*)(ws + OFF_SRT);
    unsigned short* Wb    = (unsigned short*)(ws + OFF_WB);
    unsigned short* xb    = (unsigned short*)(ws + OFF_XB);
    unsigned short* meanb = (unsigned short*)(ws + OFF_MEAN);
    unsigned short* h1b   = (unsigned short*)(ws + OFF_H1);
    unsigned short* W1lb = Wb;
    unsigned short* W1rb = Wb + 16384;
    unsigned short* W2lb = Wb + 32768;
    unsigned short* W2rb = Wb + 49152;

    // 1: conversions + zero deg + fmt detect
    cvt_all<<<5221, 256, 0, stream>>>(x, xb, W1l, W1r, W2l, W2r, Wb, deg, ei, fmtflag);
    // 2-5: CSR build
    count_deg<<<(NE + 255) / 256, 256, 0, stream>>>(ei, fmtflag, deg);
    block_sums<<<NBLK, 256, 0, stream>>>(deg, bsum);
    scan_block2<<<NBLK, 256, 0, stream>>>(deg, bsum, row_ptr, cursor);
    fill_csr<<<(NE + 255) / 256, 256, 0, stream>>>(ei, fmtflag, cursor, sorted);

    // 6-7: layer 1
    aggregate_g<<<NN / 16, 256, 0, stream>>>(xb, row_ptr, sorted, meanb);
    sage_gemm<false><<<dim3(NN / 64, 2), 256, 0, stream>>>(meanb, xb, W1lb, W1rb, b1l, h1b);

    // 8-9: layer 2
    aggregate_g<<<NN / 16, 256, 0, stream>>>(h1b, row_ptr, sorted, meanb);
    sage_gemm<true><<<dim3(NN / 64, 2), 256, 0, stream>>>(meanb, h1b, W2lb, W2rb, b2l, out);
}

// Round 2
// 233.831 us; speedup vs baseline: 1.0636x; 1.0636x over previous
//
#include <hip/hip_runtime.h>
#include <hip/hip_bf16.h>

#define DIM 128
#define NN 40000
#define NE 640000
#define NBLK ((NN + 255) / 256)   // 157

// gfx950 bf16 MFMA fragment types (learn_hip m89/m93/m97):
typedef __attribute__((ext_vector_type(8))) short s16x8;   // 8 bf16 in 4 VGPRs
typedef __attribute__((ext_vector_type(4))) float f32x4;
typedef __attribute__((ext_vector_type(4))) unsigned short u16x4;
typedef __attribute__((ext_vector_type(4))) unsigned int u32x4;

__device__ __forceinline__ float bf16_lo(unsigned v) { return __uint_as_float(v << 16); }
__device__ __forceinline__ float bf16_hi(unsigned v) { return __uint_as_float(v & 0xffff0000u); }
__device__ __forceinline__ unsigned short f_to_bf16(float f) {
    unsigned u = __float_as_uint(f);
    u += 0x7fffu + ((u >> 16) & 1u);   // round-to-nearest-even
    return (unsigned short)(u >> 16);
}

__global__ void fill_const_f32(float* __restrict__ out, int n, float v) {
    int i = blockIdx.x * blockDim.x + threadIdx.x;
    if (i < n) out[i] = v;
}

// ---------------- fused: fp32->bf16 cvt (x + weights) + zero deg + fmt detect ----
// blocks 0..4999: x (4 elems/thread); 5000..5063: weights; 5064..5220: zero deg
// (+ block 5064 lanes 0..63 detect int64-vs-int32 edge_index).
__global__ void cvt_all(const float* __restrict__ x, unsigned short* __restrict__ xb,
                        const float* __restrict__ w0, const float* __restrict__ w1,
                        const float* __restrict__ w2, const float* __restrict__ w3,
                        unsigned short* __restrict__ wb,
                        int* __restrict__ deg, const int* __restrict__ ei,
                        int* __restrict__ flag) {
    int b = blockIdx.x;
    if (b >= 5064) {
        int i = (b - 5064) * 256 + threadIdx.x;
        if (i < NN) deg[i] = 0;
        if (b == 5064 && threadIdx.x < 64) {
            // int64 passthrough: odd words (high halves, values < 40000) all zero
            int w = ei[2 * threadIdx.x + 1];
            unsigned long long m = __ballot(w == 0);
            if (threadIdx.x == 0) *flag = (m == ~0ull) ? 1 : 0;   // 1 = int64
        }
        return;
    }
    const float* src;
    unsigned short* dst;
    size_t i;
    if (b < 5000) {
        src = x; dst = xb;
        i = (size_t)b * 256 + threadIdx.x;           // 1,280,000 f32x4 groups
    } else {
        int w = b - 5000;
        int m = w >> 4;                               // matrix 0..3
        src = (m == 0) ? w0 : (m == 1) ? w1 : (m == 2) ? w2 : w3;
        dst = wb + (size_t)m * 16384;
        i = (size_t)(w & 15) * 256 + threadIdx.x;     // 4096 groups per matrix
    }
    f32x4 v = *(const f32x4*)(src + 4 * i);
    u16x4 o;
    o.x = f_to_bf16(v.x); o.y = f_to_bf16(v.y);
    o.z = f_to_bf16(v.z); o.w = f_to_bf16(v.w);
    *(u16x4*)(dst + 4 * i) = o;
}

// ---------------- CSR build ----------------

__global__ void count_deg(const int* __restrict__ ei, const int* __restrict__ fmt,
                          int* __restrict__ deg) {
    int e = blockIdx.x * blockDim.x + threadIdx.x;
    if (e >= NE) return;
    int dst = (*fmt) ? ((const int2*)ei)[NE + e].x : ei[NE + e];
    if ((unsigned)dst < (unsigned)NN) atomicAdd(&deg[dst], 1);
}

__global__ void block_sums(const int* __restrict__ deg, int* __restrict__ bsum) {
    __shared__ int sh[256];
    int i = blockIdx.x * 256 + threadIdx.x;
    sh[threadIdx.x] = (i < NN) ? deg[i] : 0;
    __syncthreads();
    for (int off = 128; off > 0; off >>= 1) {
        if (threadIdx.x < off) sh[threadIdx.x] += sh[threadIdx.x + off];
        __syncthreads();
    }
    if (threadIdx.x == 0) bsum[blockIdx.x] = sh[0];
}

// merged scan: each block redundantly LDS-scans the 157 block sums (8 steps,
// no serial tail) to get its base, then local-scans its 256 deg entries.
__global__ void scan_block2(const int* __restrict__ deg, const int* __restrict__ bsum,
                            int* __restrict__ row_ptr, int* __restrict__ cursor) {
    __shared__ int sh[256];
    int t = threadIdx.x, bid = blockIdx.x;

    int v0 = (t < NBLK) ? bsum[t] : 0;
    sh[t] = v0;
    __syncthreads();
    for (int off = 1; off < 256; off <<= 1) {
        int u = (t >= off) ? sh[t - off] : 0;
        __syncthreads();
        sh[t] += u;
        __syncthreads();
    }
    int base = sh[bid] - bsum[bid];   // exclusive prefix of earlier chunks
    __syncthreads();

    int i = bid * 256 + t;
    int v = (i < NN) ? deg[i] : 0;
    sh[t] = v;
    __syncthreads();
    for (int off = 1; off < 256; off <<= 1) {
        int u = (t >= off) ? sh[t - off] : 0;
        __syncthreads();
        sh[t] += u;
        __syncthreads();
    }
    int excl = sh[t] - v + base;
    if (i < NN) { row_ptr[i] = excl; cursor[i] = excl; }
    if (i == NN - 1) row_ptr[NN] = excl + v;
}

__global__ void fill_csr(const int* __restrict__ ei, const int* __restrict__ fmt,
                         int* __restrict__ cursor, int* __restrict__ sorted_src) {
    int e = blockIdx.x * blockDim.x + threadIdx.x;
    if (e >= NE) return;
    int src, dst;
    if (*fmt) {
        src = ((const int2*)ei)[e].x;
        dst = ((const int2*)ei)[NE + e].x;
    } else {
        src = ei[e];
        dst = ei[NE + e];
    }
    if ((unsigned)dst >= (unsigned)NN) return;
    int pos = atomicAdd(&cursor[dst], 1);
    if ((unsigned)pos < (unsigned)NE) sorted_src[pos] = src;
}

// ---------------- fused layer: aggregate(64 nodes) -> LDS frag layout -> GEMM ----
// v3 (this round): mean never touches global. Block owns 64 nodes.
//  Phase A: stage hself rows [row0,row0+64) into LDS in MFMA A-frag layout.
//  Phase B: 16 groups (16 lanes each) aggregate 4 nodes apiece (r1-proven gather
//           body), scale, cvt bf16, write into LDS frag layout.
//  Phase C: proven MFMA loop; A-frags are ds_read_b128 at base+lane*16
//           (stride-1, conflict-free); B-frags from global (L2-hot, 64KB).
// Frag-layout address (bytes): t*4096 + kb*1024 + quad*256 + m*16
//   where node_in_block nb = t*16+m, element e = kb*32+quad*8+j.
//   GEMM lane L (m=L&15, quad=L>>4) reads t*4096 + kb*1024 + L*16.  [checked]

#define ACC8(A, v)                                 \
    A[0] += bf16_lo((v).x); A[1] += bf16_hi((v).x); \
    A[2] += bf16_lo((v).y); A[3] += bf16_hi((v).y); \
    A[4] += bf16_lo((v).z); A[5] += bf16_hi((v).z); \
    A[6] += bf16_lo((v).w); A[7] += bf16_hi((v).w);

template <bool WRITE_F32>
__global__ __launch_bounds__(256) void sage_layer(
    const unsigned short* __restrict__ xin,    // gather table / self features
    const int* __restrict__ row_ptr,
    const int* __restrict__ sorted_src,
    const unsigned short* __restrict__ Wl,     // [128,128] bf16
    const unsigned short* __restrict__ Wr,
    const float* __restrict__ bias,            // [128] fp32
    void* __restrict__ outv) {
    __shared__ unsigned short lds_mean[64 * 128];  // 16 KB, frag layout
    __shared__ unsigned short lds_hs[64 * 128];    // 16 KB, frag layout

    int tid = threadIdx.x;
    int lane = tid & 63;
    int wv = tid >> 6;
    int row0 = blockIdx.x * 64;

    // ---- Phase A: stage hself rows (coalesced global read, frag-layout write) ----
    {
        int r = tid >> 2;                      // row-in-block 0..63
        int c4 = tid & 3;                      // 64B quarter of the row
        const unsigned short* src = xin + (size_t)(row0 + r) * DIM + c4 * 32;
#pragma unroll
        for (int c = 0; c < 4; ++c) {
            int lid = c4 * 4 + c;              // 16B chunk 0..15
            u32x4 v = *(const u32x4*)(src + c * 8);
            int off = (r >> 4) * 2048 + (lid >> 2) * 512 + (lid & 3) * 128 + (r & 15) * 8;
            *(u32x4*)(lds_hs + off) = v;
        }
    }

    // ---- Phase B: aggregate 4 nodes per 16-lane group ----
    {
        int grp = lane >> 4;
        int lid = lane & 15;
        int gbase = grp << 4;
        for (int it = 0; it < 4; ++it) {
            int nb = wv * 16 + it * 4 + grp;   // node in block
            int n = row0 + nb;
            int start = row_ptr[n], end = row_ptr[n + 1];

            float a[8] = {0.f, 0.f, 0.f, 0.f, 0.f, 0.f, 0.f, 0.f};
            float b[8] = {0.f, 0.f, 0.f, 0.f, 0.f, 0.f, 0.f, 0.f};

            int i = start;
            for (; i + 16 <= end; i += 16) {
                int idx = sorted_src[i + lid];
#pragma unroll
                for (int j = 0; j < 16; j += 4) {
                    int s0 = __shfl(idx, gbase + j);
                    int s1 = __shfl(idx, gbase + j + 1);
                    int s2 = __shfl(idx, gbase + j + 2);
                    int s3 = __shfl(idx, gbase + j + 3);
                    u32x4 v0 = *(const u32x4*)(xin + (size_t)s0 * DIM + lid * 8);
                    u32x4 v1 = *(const u32x4*)(xin + (size_t)s1 * DIM + lid * 8);
                    u32x4 v2 = *(const u32x4*)(xin + (size_t)s2 * DIM + lid * 8);
                    u32x4 v3 = *(const u32x4*)(xin + (size_t)s3 * DIM + lid * 8);
                    ACC8(a, v0);
                    ACC8(b, v1);
                    ACC8(a, v2);
                    ACC8(b, v3);
                }
            }
            int rem = end - i;
            if (rem > 0) {
                int src_i = (i + lid < end) ? (i + lid) : (end - 1);
                int idx = sorted_src[src_i];
#pragma unroll
                for (int j = 0; j < 16; ++j) {
                    if (j < rem) {
                        int s = __shfl(idx, gbase + j);
                        u32x4 v = *(const u32x4*)(xin + (size_t)s * DIM + lid * 8);
                        if (j & 1) { ACC8(b, v); }
                        else       { ACC8(a, v); }
                    }
                }
            }
#pragma unroll
            for (int k = 0; k < 8; ++k) a[k] += b[k];

            int d = end - start;
            float inv = 1.f / (float)(d > 1 ? d : 1);
            u32x4 o;
            o.x = (unsigned)f_to_bf16(a[0] * inv) | ((unsigned)f_to_bf16(a[1] * inv) << 16);
            o.y = (unsigned)f_to_bf16(a[2] * inv) | ((unsigned)f_to_bf16(a[3] * inv) << 16);
            o.z = (unsigned)f_to_bf16(a[4] * inv) | ((unsigned)f_to_bf16(a[5] * inv) << 16);
            o.w = (unsigned)f_to_bf16(a[6] * inv) | ((unsigned)f_to_bf16(a[7] * inv) << 16);
            int off = (nb >> 4) * 2048 + (lid >> 2) * 512 + (lid & 3) * 128 + (nb & 15) * 8;
            *(u32x4*)(lds_mean + off) = o;
        }
    }

    __syncthreads();

    // ---- Phase C: GEMM.  Each wave: 64 rows x 16 cols, looped over 2 col-halves ----
    {
        int quad = lane >> 4;
        int m16 = lane & 15;
        int lo = lane * 8;                     // shorts offset within (t,kb) block
#pragma unroll
        for (int ch = 0; ch < 2; ++ch) {
            int bcol = ch * 64 + wv * 16 + m16;
            const unsigned short* wl0 = Wl + (size_t)bcol * DIM + quad * 8;
            const unsigned short* wr0 = Wr + (size_t)bcol * DIM + quad * 8;
            s16x8 bl[4], br[4];
#pragma unroll
            for (int kb = 0; kb < 4; ++kb) {
                bl[kb] = *(const s16x8*)(wl0 + kb * 32);
                br[kb] = *(const s16x8*)(wr0 + kb * 32);
            }
            f32x4 acc[4] = {{0,0,0,0},{0,0,0,0},{0,0,0,0},{0,0,0,0}};
#pragma unroll
            for (int t = 0; t < 4; ++t) {
#pragma unroll
                for (int kb = 0; kb < 4; ++kb) {
                    s16x8 am = *(const s16x8*)(lds_mean + t * 2048 + kb * 512 + lo);
                    acc[t] = __builtin_amdgcn_mfma_f32_16x16x32_bf16(am, bl[kb], acc[t], 0, 0, 0);
                }
#pragma unroll
                for (int kb = 0; kb < 4; ++kb) {
                    s16x8 ah = *(const s16x8*)(lds_hs + t * 2048 + kb * 512 + lo);
                    acc[t] = __builtin_amdgcn_mfma_f32_16x16x32_bf16(ah, br[kb], acc[t], 0, 0, 0);
                }
            }
            float bv = bias[bcol];
#pragma unroll
            for (int t = 0; t < 4; ++t) {
#pragma unroll
                for (int r = 0; r < 4; ++r) {
                    int orow = row0 + t * 16 + quad * 4 + r;
                    float v = fmaxf(acc[t][r] + bv, 0.f);   // relu
                    if (WRITE_F32)
                        ((float*)outv)[(size_t)orow * DIM + bcol] = v;
                    else
                        ((unsigned short*)outv)[(size_t)orow * DIM + bcol] = f_to_bf16(v);
                }
            }
        }
    }
}

// ---------------- launch ----------------

extern "C" void kernel_launch(void* const* d_in, const int* in_sizes, int n_in,
                              void* d_out, int out_size, void* d_ws, size_t ws_size,
                              hipStream_t stream) {
    const float* x   = (const float*)d_in[0];
    const int*   ei  = (const int*)d_in[1];
    const float* W1l = (const float*)d_in[2];
    const float* b1l = (const float*)d_in[3];
    const float* W1r = (const float*)d_in[4];
    const float* W2l = (const float*)d_in[5];
    const float* b2l = (const float*)d_in[6];
    const float* W2r = (const float*)d_in[7];
    float* out = (float*)d_out;

    const int OUT_ELEMS = NN * DIM;        // 5,120,000

    // workspace layout (256B-aligned)
    const size_t OFF_DEG  = 0;             // N ints
    const size_t OFF_ROW  = 163840;        // N+1 ints
    const size_t OFF_BSUM = 324608;        // NBLK ints (in ROW region slack)
    const size_t OFF_CUR  = 327680;        // N ints
    const size_t OFF_FMT  = 491264;        // 1 int
    const size_t OFF_SRT  = 491520;        // E ints
    const size_t OFF_WB   = 3051520;       // 4 * 16384 bf16
    const size_t OFF_XB   = 3182592;       // N*128 bf16
    const size_t OFF_H1   = 23662592;      // N*128 bf16 (MEAN slot now unused)
    const size_t NEEDED   = 33902592;

    if (ws_size < NEEDED) {
        fill_const_f32<<<(OUT_ELEMS + 255) / 256, 256, 0, stream>>>(out, OUT_ELEMS, 50.0f);
        return;
    }

    char* ws = (char*)d_ws;
    int* deg     = (int*)(ws + OFF_DEG);
    int* row_ptr = (int*)(ws + OFF_ROW);
    int* bsum    = (int*)(ws + OFF_BSUM);
    int* cursor  = (int*)(ws + OFF_CUR);
    int* fmtflag = (int*)(ws + OFF_FMT);
    int* sorted  = (int*)(ws + OFF_SRT);
    unsigned short* Wb    = (unsigned short*)(ws + OFF_WB);
    unsigned short* xb    = (unsigned short*)(ws + OFF_XB);
    unsigned short* h1b   = (unsigned short*)(ws + OFF_H1);
    unsigned short* W1lb = Wb;
    unsigned short* W1rb = Wb + 16384;
    unsigned short* W2lb = Wb + 32768;
    unsigned short* W2rb = Wb + 49152;

    // 1: conversions + zero deg + fmt detect
    cvt_all<<<5221, 256, 0, stream>>>(x, xb, W1l, W1r, W2l, W2r, Wb, deg, ei, fmtflag);
    // 2-5: CSR build
    count_deg<<<(NE + 255) / 256, 256, 0, stream>>>(ei, fmtflag, deg);
    block_sums<<<NBLK, 256, 0, stream>>>(deg, bsum);
    scan_block2<<<NBLK, 256, 0, stream>>>(deg, bsum, row_ptr, cursor);
    fill_csr<<<(NE + 255) / 256, 256, 0, stream>>>(ei, fmtflag, cursor, sorted);

    // 6: layer 1 (fused aggregate+GEMM)
    sage_layer<false><<<NN / 64, 256, 0, stream>>>(xb, row_ptr, sorted, W1lb, W1rb, b1l, h1b);
    // 7: layer 2 (fused aggregate+GEMM)
    sage_layer<true><<<NN / 64, 256, 0, stream>>>(h1b, row_ptr, sorted, W2lb, W2rb, b2l, out);
}

// Round 3
// 229.926 us; speedup vs baseline: 1.0817x; 1.0170x over previous
//
#include <hip/hip_runtime.h>
#include <hip/hip_bf16.h>

#define DIM 128
#define NN 40000
#define NE 640000
#define NBLK ((NN + 255) / 256)   // 157

// gfx950 bf16 MFMA fragment types (learn_hip m89/m93/m97):
typedef __attribute__((ext_vector_type(8))) short s16x8;   // 8 bf16 in 4 VGPRs
typedef __attribute__((ext_vector_type(4))) float f32x4;
typedef __attribute__((ext_vector_type(4))) unsigned short u16x4;
typedef __attribute__((ext_vector_type(4))) unsigned int u32x4;

__device__ __forceinline__ float bf16_lo(unsigned v) { return __uint_as_float(v << 16); }
__device__ __forceinline__ float bf16_hi(unsigned v) { return __uint_as_float(v & 0xffff0000u); }
__device__ __forceinline__ unsigned short f_to_bf16(float f) {
    unsigned u = __float_as_uint(f);
    u += 0x7fffu + ((u >> 16) & 1u);   // round-to-nearest-even
    return (unsigned short)(u >> 16);
}

__global__ void fill_const_f32(float* __restrict__ out, int n, float v) {
    int i = blockIdx.x * blockDim.x + threadIdx.x;
    if (i < n) out[i] = v;
}

// ---------------- fused: fp32->bf16 cvt (x + weights) + zero deg + fmt detect ----
// blocks 0..4999: x (4 elems/thread); 5000..5063: weights; 5064..5220: zero deg
// (+ block 5064 lanes 0..63 detect int64-vs-int32 edge_index).
__global__ void cvt_all(const float* __restrict__ x, unsigned short* __restrict__ xb,
                        const float* __restrict__ w0, const float* __restrict__ w1,
                        const float* __restrict__ w2, const float* __restrict__ w3,
                        unsigned short* __restrict__ wb,
                        int* __restrict__ deg, const int* __restrict__ ei,
                        int* __restrict__ flag) {
    int b = blockIdx.x;
    if (b >= 5064) {
        int i = (b - 5064) * 256 + threadIdx.x;
        if (i < NN) deg[i] = 0;
        if (b == 5064 && threadIdx.x < 64) {
            // int64 passthrough: odd words (high halves, values < 40000) all zero
            int w = ei[2 * threadIdx.x + 1];
            unsigned long long m = __ballot(w == 0);
            if (threadIdx.x == 0) *flag = (m == ~0ull) ? 1 : 0;   // 1 = int64
        }
        return;
    }
    const float* src;
    unsigned short* dst;
    size_t i;
    if (b < 5000) {
        src = x; dst = xb;
        i = (size_t)b * 256 + threadIdx.x;           // 1,280,000 f32x4 groups
    } else {
        int w = b - 5000;
        int m = w >> 4;                               // matrix 0..3
        src = (m == 0) ? w0 : (m == 1) ? w1 : (m == 2) ? w2 : w3;
        dst = wb + (size_t)m * 16384;
        i = (size_t)(w & 15) * 256 + threadIdx.x;     // 4096 groups per matrix
    }
    f32x4 v = *(const f32x4*)(src + 4 * i);
    u16x4 o;
    o.x = f_to_bf16(v.x); o.y = f_to_bf16(v.y);
    o.z = f_to_bf16(v.z); o.w = f_to_bf16(v.w);
    *(u16x4*)(dst + 4 * i) = o;
}

// ---------------- CSR build ----------------

__global__ void count_deg(const int* __restrict__ ei, const int* __restrict__ fmt,
                          int* __restrict__ deg) {
    int e = blockIdx.x * blockDim.x + threadIdx.x;
    if (e >= NE) return;
    int dst = (*fmt) ? ((const int2*)ei)[NE + e].x : ei[NE + e];
    if ((unsigned)dst < (unsigned)NN) atomicAdd(&deg[dst], 1);
}

__global__ void block_sums(const int* __restrict__ deg, int* __restrict__ bsum) {
    __shared__ int sh[256];
    int i = blockIdx.x * 256 + threadIdx.x;
    sh[threadIdx.x] = (i < NN) ? deg[i] : 0;
    __syncthreads();
    for (int off = 128; off > 0; off >>= 1) {
        if (threadIdx.x < off) sh[threadIdx.x] += sh[threadIdx.x + off];
        __syncthreads();
    }
    if (threadIdx.x == 0) bsum[blockIdx.x] = sh[0];
}

// merged scan: each block redundantly LDS-scans the 157 block sums (8 steps,
// no serial tail) to get its base, then local-scans its 256 deg entries.
__global__ void scan_block2(const int* __restrict__ deg, const int* __restrict__ bsum,
                            int* __restrict__ row_ptr, int* __restrict__ cursor) {
    __shared__ int sh[256];
    int t = threadIdx.x, bid = blockIdx.x;

    int v0 = (t < NBLK) ? bsum[t] : 0;
    sh[t] = v0;
    __syncthreads();
    for (int off = 1; off < 256; off <<= 1) {
        int u = (t >= off) ? sh[t - off] : 0;
        __syncthreads();
        sh[t] += u;
        __syncthreads();
    }
    int base = sh[bid] - bsum[bid];   // exclusive prefix of earlier chunks
    __syncthreads();

    int i = bid * 256 + t;
    int v = (i < NN) ? deg[i] : 0;
    sh[t] = v;
    __syncthreads();
    for (int off = 1; off < 256; off <<= 1) {
        int u = (t >= off) ? sh[t - off] : 0;
        __syncthreads();
        sh[t] += u;
        __syncthreads();
    }
    int excl = sh[t] - v + base;
    if (i < NN) { row_ptr[i] = excl; cursor[i] = excl; }
    if (i == NN - 1) row_ptr[NN] = excl + v;
}

__global__ void fill_csr(const int* __restrict__ ei, const int* __restrict__ fmt,
                         int* __restrict__ cursor, int* __restrict__ sorted_src) {
    int e = blockIdx.x * blockDim.x + threadIdx.x;
    if (e >= NE) return;
    int src, dst;
    if (*fmt) {
        src = ((const int2*)ei)[e].x;
        dst = ((const int2*)ei)[NE + e].x;
    } else {
        src = ei[e];
        dst = ei[NE + e];
    }
    if ((unsigned)dst >= (unsigned)NN) return;
    int pos = atomicAdd(&cursor[dst], 1);
    if ((unsigned)pos < (unsigned)NE) sorted_src[pos] = src;
}

// ---------------- fused layer: aggregate(64 nodes) -> LDS frag layout -> GEMM ----
// v4 (this round): 512 threads / 8 waves per 64-node block (r2 counters showed
// 19.7% occupancy: grid 625 x 4 waves = ~2.4 blocks/CU was the cap; 8 waves
// doubles resident waves during the latency-bound gather).  LDS frag layout now
// XOR-swizzled by chunk index (m_slot ^= lid): write side 16-way -> 2-way bank
// conflict (r2: SQ_LDS_BANK_CONFLICT=800K), read side stays conflict-free
// (wave covers a contiguous 1KB region per (t,kb); XOR is bijective within it).
// Address (shorts): (nb>>4)*2048 + (lid>>2)*512 + (lid&3)*128 + ((nb&15)^lid)*8
//   write: node nb, 16B chunk lid (elements lid*8..+7).
//   read : lane L (m=L&15, quad=L>>4), kb -> lid=kb*4+quad:
//          t*2048 + kb*512 + ((L ^ (kb*4+quad)) * 8).    [verified bijective]

#define ACC8(A, v)                                 \
    A[0] += bf16_lo((v).x); A[1] += bf16_hi((v).x); \
    A[2] += bf16_lo((v).y); A[3] += bf16_hi((v).y); \
    A[4] += bf16_lo((v).z); A[5] += bf16_hi((v).z); \
    A[6] += bf16_lo((v).w); A[7] += bf16_hi((v).w);

template <bool WRITE_F32>
__global__ __launch_bounds__(512) void sage_layer(
    const unsigned short* __restrict__ xin,    // gather table / self features
    const int* __restrict__ row_ptr,
    const int* __restrict__ sorted_src,
    const unsigned short* __restrict__ Wl,     // [128,128] bf16
    const unsigned short* __restrict__ Wr,
    const float* __restrict__ bias,            // [128] fp32
    void* __restrict__ outv) {
    __shared__ unsigned short lds_mean[64 * 128];  // 16 KB, swizzled frag layout
    __shared__ unsigned short lds_hs[64 * 128];    // 16 KB, swizzled frag layout

    int tid = threadIdx.x;
    int lane = tid & 63;
    int wv = tid >> 6;                 // 0..7
    int row0 = blockIdx.x * 64;

    // ---- Phase A: stage hself rows (coalesced global read, swizzled LDS write) ----
    {
        int r = tid >> 3;                      // row-in-block 0..63
        int lid0 = (tid & 7) * 2;              // 16B chunk 0,2,..,14
        int lid1 = lid0 + 1;
        const unsigned short* src = xin + (size_t)(row0 + r) * DIM + lid0 * 8;
        u32x4 v0 = *(const u32x4*)(src);
        u32x4 v1 = *(const u32x4*)(src + 8);
        int base = (r >> 4) * 2048;
        int o0 = base + (lid0 >> 2) * 512 + (lid0 & 3) * 128 + (((r & 15) ^ lid0) * 8);
        int o1 = base + (lid1 >> 2) * 512 + (lid1 & 3) * 128 + (((r & 15) ^ lid1) * 8);
        *(u32x4*)(lds_hs + o0) = v0;
        *(u32x4*)(lds_hs + o1) = v1;
    }

    // ---- Phase B: aggregate 2 nodes per 16-lane group (32 groups) ----
    {
        int grp = lane >> 4;
        int lid = lane & 15;
        int gbase = grp << 4;
        int g = wv * 4 + grp;                  // group id 0..31
        for (int it = 0; it < 2; ++it) {
            int nb = it * 32 + g;              // node in block
            int n = row0 + nb;
            int start = row_ptr[n], end = row_ptr[n + 1];

            float a[8] = {0.f, 0.f, 0.f, 0.f, 0.f, 0.f, 0.f, 0.f};
            float b[8] = {0.f, 0.f, 0.f, 0.f, 0.f, 0.f, 0.f, 0.f};

            int i = start;
            for (; i + 16 <= end; i += 16) {
                int idx = sorted_src[i + lid];
#pragma unroll
                for (int j = 0; j < 16; j += 4) {
                    int s0 = __shfl(idx, gbase + j);
                    int s1 = __shfl(idx, gbase + j + 1);
                    int s2 = __shfl(idx, gbase + j + 2);
                    int s3 = __shfl(idx, gbase + j + 3);
                    u32x4 v0 = *(const u32x4*)(xin + (size_t)s0 * DIM + lid * 8);
                    u32x4 v1 = *(const u32x4*)(xin + (size_t)s1 * DIM + lid * 8);
                    u32x4 v2 = *(const u32x4*)(xin + (size_t)s2 * DIM + lid * 8);
                    u32x4 v3 = *(const u32x4*)(xin + (size_t)s3 * DIM + lid * 8);
                    ACC8(a, v0);
                    ACC8(b, v1);
                    ACC8(a, v2);
                    ACC8(b, v3);
                }
            }
            int rem = end - i;
            if (rem > 0) {
                int src_i = (i + lid < end) ? (i + lid) : (end - 1);
                int idx = sorted_src[src_i];
#pragma unroll
                for (int j = 0; j < 16; ++j) {
                    if (j < rem) {
                        int s = __shfl(idx, gbase + j);
                        u32x4 v = *(const u32x4*)(xin + (size_t)s * DIM + lid * 8);
                        if (j & 1) { ACC8(b, v); }
                        else       { ACC8(a, v); }
                    }
                }
            }
#pragma unroll
            for (int k = 0; k < 8; ++k) a[k] += b[k];

            int d = end - start;
            float inv = 1.f / (float)(d > 1 ? d : 1);
            u32x4 o;
            o.x = (unsigned)f_to_bf16(a[0] * inv) | ((unsigned)f_to_bf16(a[1] * inv) << 16);
            o.y = (unsigned)f_to_bf16(a[2] * inv) | ((unsigned)f_to_bf16(a[3] * inv) << 16);
            o.z = (unsigned)f_to_bf16(a[4] * inv) | ((unsigned)f_to_bf16(a[5] * inv) << 16);
            o.w = (unsigned)f_to_bf16(a[6] * inv) | ((unsigned)f_to_bf16(a[7] * inv) << 16);
            int off = (nb >> 4) * 2048 + (lid >> 2) * 512 + (lid & 3) * 128
                    + (((nb & 15) ^ lid) * 8);
            *(u32x4*)(lds_mean + off) = o;
        }
    }

    __syncthreads();

    // ---- Phase C: GEMM. 8 waves x (64 rows x 16 cols) covers 64x128 ----
    {
        int quad = lane >> 4;
        int m16 = lane & 15;
        int bcol = wv * 16 + m16;              // 0..127
        const unsigned short* wl0 = Wl + (size_t)bcol * DIM + quad * 8;
        const unsigned short* wr0 = Wr + (size_t)bcol * DIM + quad * 8;
        s16x8 bl[4], br[4];
#pragma unroll
        for (int kb = 0; kb < 4; ++kb) {
            bl[kb] = *(const s16x8*)(wl0 + kb * 32);
            br[kb] = *(const s16x8*)(wr0 + kb * 32);
        }
        f32x4 acc[4] = {{0,0,0,0},{0,0,0,0},{0,0,0,0},{0,0,0,0}};
#pragma unroll
        for (int t = 0; t < 4; ++t) {
#pragma unroll
            for (int kb = 0; kb < 4; ++kb) {
                int lo = (lane ^ ((kb << 2) | quad)) << 3;
                s16x8 am = *(const s16x8*)(lds_mean + t * 2048 + kb * 512 + lo);
                acc[t] = __builtin_amdgcn_mfma_f32_16x16x32_bf16(am, bl[kb], acc[t], 0, 0, 0);
            }
#pragma unroll
            for (int kb = 0; kb < 4; ++kb) {
                int lo = (lane ^ ((kb << 2) | quad)) << 3;
                s16x8 ah = *(const s16x8*)(lds_hs + t * 2048 + kb * 512 + lo);
                acc[t] = __builtin_amdgcn_mfma_f32_16x16x32_bf16(ah, br[kb], acc[t], 0, 0, 0);
            }
        }
        float bv = bias[bcol];
#pragma unroll
        for (int t = 0; t < 4; ++t) {
#pragma unroll
            for (int r = 0; r < 4; ++r) {
                int orow = row0 + t * 16 + quad * 4 + r;
                float v = fmaxf(acc[t][r] + bv, 0.f);   // relu
                if (WRITE_F32)
                    ((float*)outv)[(size_t)orow * DIM + bcol] = v;
                else
                    ((unsigned short*)outv)[(size_t)orow * DIM + bcol] = f_to_bf16(v);
            }
        }
    }
}

// ---------------- launch ----------------

extern "C" void kernel_launch(void* const* d_in, const int* in_sizes, int n_in,
                              void* d_out, int out_size, void* d_ws, size_t ws_size,
                              hipStream_t stream) {
    const float* x   = (const float*)d_in[0];
    const int*   ei  = (const int*)d_in[1];
    const float* W1l = (const float*)d_in[2];
    const float* b1l = (const float*)d_in[3];
    const float* W1r = (const float*)d_in[4];
    const float* W2l = (const float*)d_in[5];
    const float* b2l = (const float*)d_in[6];
    const float* W2r = (const float*)d_in[7];
    float* out = (float*)d_out;

    const int OUT_ELEMS = NN * DIM;        // 5,120,000

    // workspace layout (256B-aligned)
    const size_t OFF_DEG  = 0;             // N ints
    const size_t OFF_ROW  = 163840;        // N+1 ints
    const size_t OFF_BSUM = 324608;        // NBLK ints (in ROW region slack)
    const size_t OFF_CUR  = 327680;        // N ints
    const size_t OFF_FMT  = 491264;        // 1 int
    const size_t OFF_SRT  = 491520;        // E ints
    const size_t OFF_WB   = 3051520;       // 4 * 16384 bf16
    const size_t OFF_XB   = 3182592;       // N*128 bf16
    const size_t OFF_H1   = 23662592;      // N*128 bf16 (MEAN slot unused)
    const size_t NEEDED   = 33902592;

    if (ws_size < NEEDED) {
        fill_const_f32<<<(OUT_ELEMS + 255) / 256, 256, 0, stream>>>(out, OUT_ELEMS, 50.0f);
        return;
    }

    char* ws = (char*)d_ws;
    int* deg     = (int*)(ws + OFF_DEG);
    int* row_ptr = (int*)(ws + OFF_ROW);
    int* bsum    = (int*)(ws + OFF_BSUM);
    int* cursor  = (int*)(ws + OFF_CUR);
    int* fmtflag = (int*)(ws + OFF_FMT);
    int* sorted  = (int*)(ws + OFF_SRT);
    unsigned short* Wb    = (unsigned short*)(ws + OFF_WB);
    unsigned short* xb    = (unsigned short*)(ws + OFF_XB);
    unsigned short* h1b   = (unsigned short*)(ws + OFF_H1);
    unsigned short* W1lb = Wb;
    unsigned short* W1rb = Wb + 16384;
    unsigned short* W2lb = Wb + 32768;
    unsigned short* W2rb = Wb + 49152;

    // 1: conversions + zero deg + fmt detect
    cvt_all<<<5221, 256, 0, stream>>>(x, xb, W1l, W1r, W2l, W2r, Wb, deg, ei, fmtflag);
    // 2-5: CSR build
    count_deg<<<(NE + 255) / 256, 256, 0, stream>>>(ei, fmtflag, deg);
    block_sums<<<NBLK, 256, 0, stream>>>(deg, bsum);
    scan_block2<<<NBLK, 256, 0, stream>>>(deg, bsum, row_ptr, cursor);
    fill_csr<<<(NE + 255) / 256, 256, 0, stream>>>(ei, fmtflag, cursor, sorted);

    // 6: layer 1 (fused aggregate+GEMM, 8 waves/block)
    sage_layer<false><<<NN / 64, 512, 0, stream>>>(xb, row_ptr, sorted, W1lb, W1rb, b1l, h1b);
    // 7: layer 2 (fused aggregate+GEMM, 8 waves/block)
    sage_layer<true><<<NN / 64, 512, 0, stream>>>(h1b, row_ptr, sorted, W2lb, W2rb, b2l, out);
}

// Round 4
// 208.319 us; speedup vs baseline: 1.1939x; 1.1037x over previous
//
#include <hip/hip_runtime.h>
#include <hip/hip_bf16.h>

#define DIM 128
#define NN 40000
#define NE 640000
#define NBLK ((NN + 255) / 256)   // 157

// gfx950 bf16 MFMA fragment types (learn_hip m89/m93/m97):
typedef __attribute__((ext_vector_type(8))) short s16x8;   // 8 bf16 in 4 VGPRs
typedef __attribute__((ext_vector_type(4))) float f32x4;
typedef __attribute__((ext_vector_type(4))) unsigned short u16x4;
typedef __attribute__((ext_vector_type(4))) unsigned int u32x4;

__device__ __forceinline__ float bf16_lo(unsigned v) { return __uint_as_float(v << 16); }
__device__ __forceinline__ float bf16_hi(unsigned v) { return __uint_as_float(v & 0xffff0000u); }
__device__ __forceinline__ unsigned short f_to_bf16(float f) {
    unsigned u = __float_as_uint(f);
    u += 0x7fffu + ((u >> 16) & 1u);   // round-to-nearest-even
    return (unsigned short)(u >> 16);
}

__global__ void fill_const_f32(float* __restrict__ out, int n, float v) {
    int i = blockIdx.x * blockDim.x + threadIdx.x;
    if (i < n) out[i] = v;
}

// ---------------- fused: fp32->bf16 cvt (x + weights) + zero deg + fmt detect ----
// blocks 0..4999: x (4 elems/thread); 5000..5063: weights; 5064..5220: zero deg
// (+ block 5064 lanes 0..63 detect int64-vs-int32 edge_index).
__global__ void cvt_all(const float* __restrict__ x, unsigned short* __restrict__ xb,
                        const float* __restrict__ w0, const float* __restrict__ w1,
                        const float* __restrict__ w2, const float* __restrict__ w3,
                        unsigned short* __restrict__ wb,
                        int* __restrict__ deg, const int* __restrict__ ei,
                        int* __restrict__ flag) {
    int b = blockIdx.x;
    if (b >= 5064) {
        int i = (b - 5064) * 256 + threadIdx.x;
        if (i < NN) deg[i] = 0;
        if (b == 5064 && threadIdx.x < 64) {
            // int64 passthrough: odd words (high halves, values < 40000) all zero
            int w = ei[2 * threadIdx.x + 1];
            unsigned long long m = __ballot(w == 0);
            if (threadIdx.x == 0) *flag = (m == ~0ull) ? 1 : 0;   // 1 = int64
        }
        return;
    }
    const float* src;
    unsigned short* dst;
    size_t i;
    if (b < 5000) {
        src = x; dst = xb;
        i = (size_t)b * 256 + threadIdx.x;           // 1,280,000 f32x4 groups
    } else {
        int w = b - 5000;
        int m = w >> 4;                               // matrix 0..3
        src = (m == 0) ? w0 : (m == 1) ? w1 : (m == 2) ? w2 : w3;
        dst = wb + (size_t)m * 16384;
        i = (size_t)(w & 15) * 256 + threadIdx.x;     // 4096 groups per matrix
    }
    f32x4 v = *(const f32x4*)(src + 4 * i);
    u16x4 o;
    o.x = f_to_bf16(v.x); o.y = f_to_bf16(v.y);
    o.z = f_to_bf16(v.z); o.w = f_to_bf16(v.w);
    *(u16x4*)(dst + 4 * i) = o;
}

// ---------------- CSR build ----------------

__global__ void count_deg(const int* __restrict__ ei, const int* __restrict__ fmt,
                          int* __restrict__ deg) {
    int e = blockIdx.x * blockDim.x + threadIdx.x;
    if (e >= NE) return;
    int dst = (*fmt) ? ((const int2*)ei)[NE + e].x : ei[NE + e];
    if ((unsigned)dst < (unsigned)NN) atomicAdd(&deg[dst], 1);
}

__global__ void block_sums(const int* __restrict__ deg, int* __restrict__ bsum) {
    __shared__ int sh[256];
    int i = blockIdx.x * 256 + threadIdx.x;
    sh[threadIdx.x] = (i < NN) ? deg[i] : 0;
    __syncthreads();
    for (int off = 128; off > 0; off >>= 1) {
        if (threadIdx.x < off) sh[threadIdx.x] += sh[threadIdx.x + off];
        __syncthreads();
    }
    if (threadIdx.x == 0) bsum[blockIdx.x] = sh[0];
}

// merged scan: each block redundantly LDS-scans the 157 block sums (8 steps,
// no serial tail) to get its base, then local-scans its 256 deg entries.
__global__ void scan_block2(const int* __restrict__ deg, const int* __restrict__ bsum,
                            int* __restrict__ row_ptr, int* __restrict__ cursor) {
    __shared__ int sh[256];
    int t = threadIdx.x, bid = blockIdx.x;

    int v0 = (t < NBLK) ? bsum[t] : 0;
    sh[t] = v0;
    __syncthreads();
    for (int off = 1; off < 256; off <<= 1) {
        int u = (t >= off) ? sh[t - off] : 0;
        __syncthreads();
        sh[t] += u;
        __syncthreads();
    }
    int base = sh[bid] - bsum[bid];   // exclusive prefix of earlier chunks
    __syncthreads();

    int i = bid * 256 + t;
    int v = (i < NN) ? deg[i] : 0;
    sh[t] = v;
    __syncthreads();
    for (int off = 1; off < 256; off <<= 1) {
        int u = (t >= off) ? sh[t - off] : 0;
        __syncthreads();
        sh[t] += u;
        __syncthreads();
    }
    int excl = sh[t] - v + base;
    if (i < NN) { row_ptr[i] = excl; cursor[i] = excl; }
    if (i == NN - 1) row_ptr[NN] = excl + v;
}

__global__ void fill_csr(const int* __restrict__ ei, const int* __restrict__ fmt,
                         int* __restrict__ cursor, int* __restrict__ sorted_src) {
    int e = blockIdx.x * blockDim.x + threadIdx.x;
    if (e >= NE) return;
    int src, dst;
    if (*fmt) {
        src = ((const int2*)ei)[e].x;
        dst = ((const int2*)ei)[NE + e].x;
    } else {
        src = ei[e];
        dst = ei[NE + e];
    }
    if ((unsigned)dst >= (unsigned)NN) return;
    int pos = atomicAdd(&cursor[dst], 1);
    if ((unsigned)pos < (unsigned)NE) sorted_src[pos] = src;
}

// ---------------- fused layer: aggregate(64 nodes) -> LDS frag layout -> GEMM ----
// v5 (this round): remainder path made branch-free + burst-issued. r0-r3 evidence:
// the <16-edge tail (half of all edges at deg~Poisson(16)) was 16 separate
// if(j<rem){shfl;load;acc} blocks -> one s_waitcnt vmcnt(0) round-trip per edge
// (~400-900cy each). Now: clamp slot to rem-1 (duplicate loads are same-address
// L1 hits, ~free), issue 8 loads per burst, predicate accumulation via
// fmaf(w, val, acc) with w=0 for padding (exact; no accuracy change).
// LDS frag layout + XOR swizzle unchanged from v4 (read side conflict-free).

#define ACC8(A, v)                                 \
    A[0] += bf16_lo((v).x); A[1] += bf16_hi((v).x); \
    A[2] += bf16_lo((v).y); A[3] += bf16_hi((v).y); \
    A[4] += bf16_lo((v).z); A[5] += bf16_hi((v).z); \
    A[6] += bf16_lo((v).w); A[7] += bf16_hi((v).w);

#define ACC8W(A, v, w)                                         \
    A[0] = fmaf(w, bf16_lo((v).x), A[0]);                      \
    A[1] = fmaf(w, bf16_hi((v).x), A[1]);                      \
    A[2] = fmaf(w, bf16_lo((v).y), A[2]);                      \
    A[3] = fmaf(w, bf16_hi((v).y), A[3]);                      \
    A[4] = fmaf(w, bf16_lo((v).z), A[4]);                      \
    A[5] = fmaf(w, bf16_hi((v).z), A[5]);                      \
    A[6] = fmaf(w, bf16_lo((v).w), A[6]);                      \
    A[7] = fmaf(w, bf16_hi((v).w), A[7]);

template <bool WRITE_F32>
__global__ __launch_bounds__(512) void sage_layer(
    const unsigned short* __restrict__ xin,    // gather table / self features
    const int* __restrict__ row_ptr,
    const int* __restrict__ sorted_src,
    const unsigned short* __restrict__ Wl,     // [128,128] bf16
    const unsigned short* __restrict__ Wr,
    const float* __restrict__ bias,            // [128] fp32
    void* __restrict__ outv) {
    __shared__ unsigned short lds_mean[64 * 128];  // 16 KB, swizzled frag layout
    __shared__ unsigned short lds_hs[64 * 128];    // 16 KB, swizzled frag layout

    int tid = threadIdx.x;
    int lane = tid & 63;
    int wv = tid >> 6;                 // 0..7
    int row0 = blockIdx.x * 64;

    // ---- Phase A: stage hself rows (coalesced global read, swizzled LDS write) ----
    {
        int r = tid >> 3;                      // row-in-block 0..63
        int lid0 = (tid & 7) * 2;              // 16B chunk 0,2,..,14
        int lid1 = lid0 + 1;
        const unsigned short* src = xin + (size_t)(row0 + r) * DIM + lid0 * 8;
        u32x4 v0 = *(const u32x4*)(src);
        u32x4 v1 = *(const u32x4*)(src + 8);
        int base = (r >> 4) * 2048;
        int o0 = base + (lid0 >> 2) * 512 + (lid0 & 3) * 128 + (((r & 15) ^ lid0) * 8);
        int o1 = base + (lid1 >> 2) * 512 + (lid1 & 3) * 128 + (((r & 15) ^ lid1) * 8);
        *(u32x4*)(lds_hs + o0) = v0;
        *(u32x4*)(lds_hs + o1) = v1;
    }

    // ---- Phase B: aggregate 2 nodes per 16-lane group (32 groups) ----
    {
        int grp = lane >> 4;
        int lid = lane & 15;
        int gbase = grp << 4;
        int g = wv * 4 + grp;                  // group id 0..31

        // hoist both nodes' row_ptr reads ahead of the gather chains
        int n0 = row0 + g, n1 = row0 + 32 + g;
        int st0 = row_ptr[n0], en0 = row_ptr[n0 + 1];
        int st1 = row_ptr[n1], en1 = row_ptr[n1 + 1];

#pragma unroll
        for (int it = 0; it < 2; ++it) {
            int nb = it * 32 + g;              // node in block
            int start = it ? st1 : st0;
            int end   = it ? en1 : en0;

            float a[8] = {0.f, 0.f, 0.f, 0.f, 0.f, 0.f, 0.f, 0.f};
            float b[8] = {0.f, 0.f, 0.f, 0.f, 0.f, 0.f, 0.f, 0.f};

            int i = start;
            for (; i + 16 <= end; i += 16) {
                int idx = sorted_src[i + lid];
#pragma unroll
                for (int j = 0; j < 16; j += 4) {
                    int s0 = __shfl(idx, gbase + j);
                    int s1 = __shfl(idx, gbase + j + 1);
                    int s2 = __shfl(idx, gbase + j + 2);
                    int s3 = __shfl(idx, gbase + j + 3);
                    u32x4 v0 = *(const u32x4*)(xin + (size_t)s0 * DIM + lid * 8);
                    u32x4 v1 = *(const u32x4*)(xin + (size_t)s1 * DIM + lid * 8);
                    u32x4 v2 = *(const u32x4*)(xin + (size_t)s2 * DIM + lid * 8);
                    u32x4 v3 = *(const u32x4*)(xin + (size_t)s3 * DIM + lid * 8);
                    ACC8(a, v0);
                    ACC8(b, v1);
                    ACC8(a, v2);
                    ACC8(b, v3);
                }
            }
            // remainder (< 16 edges): branch-free clamped bursts of 8.
            // Slots j >= rem load row (rem-1) again (same-address -> L1 hit)
            // and accumulate with weight 0 (exact).
            int rem = end - i;
            if (rem > 0) {
                int src_i = (i + lid < end) ? (i + lid) : (end - 1);
                int idx = sorted_src[src_i];
                int rm1 = rem - 1;
#pragma unroll
                for (int j0 = 0; j0 < 16; j0 += 8) {
                    if (j0 < rem) {
                        u32x4 vv[8];
#pragma unroll
                        for (int k = 0; k < 8; ++k) {
                            int jj = j0 + k;
                            int cj = (jj < rem) ? jj : rm1;
                            int s = __shfl(idx, gbase + cj);
                            vv[k] = *(const u32x4*)(xin + (size_t)s * DIM + lid * 8);
                        }
#pragma unroll
                        for (int k = 0; k < 8; ++k) {
                            float w = (j0 + k < rem) ? 1.f : 0.f;
                            if (k & 1) { ACC8W(b, vv[k], w); }
                            else       { ACC8W(a, vv[k], w); }
                        }
                    }
                }
            }
#pragma unroll
            for (int k = 0; k < 8; ++k) a[k] += b[k];

            int d = end - start;
            float inv = 1.f / (float)(d > 1 ? d : 1);
            u32x4 o;
            o.x = (unsigned)f_to_bf16(a[0] * inv) | ((unsigned)f_to_bf16(a[1] * inv) << 16);
            o.y = (unsigned)f_to_bf16(a[2] * inv) | ((unsigned)f_to_bf16(a[3] * inv) << 16);
            o.z = (unsigned)f_to_bf16(a[4] * inv) | ((unsigned)f_to_bf16(a[5] * inv) << 16);
            o.w = (unsigned)f_to_bf16(a[6] * inv) | ((unsigned)f_to_bf16(a[7] * inv) << 16);
            int off = (nb >> 4) * 2048 + (lid >> 2) * 512 + (lid & 3) * 128
                    + (((nb & 15) ^ lid) * 8);
            *(u32x4*)(lds_mean + off) = o;
        }
    }

    __syncthreads();

    // ---- Phase C: GEMM. 8 waves x (64 rows x 16 cols) covers 64x128 ----
    {
        int quad = lane >> 4;
        int m16 = lane & 15;
        int bcol = wv * 16 + m16;              // 0..127
        const unsigned short* wl0 = Wl + (size_t)bcol * DIM + quad * 8;
        const unsigned short* wr0 = Wr + (size_t)bcol * DIM + quad * 8;
        s16x8 bl[4], br[4];
#pragma unroll
        for (int kb = 0; kb < 4; ++kb) {
            bl[kb] = *(const s16x8*)(wl0 + kb * 32);
            br[kb] = *(const s16x8*)(wr0 + kb * 32);
        }
        f32x4 acc[4] = {{0,0,0,0},{0,0,0,0},{0,0,0,0},{0,0,0,0}};
#pragma unroll
        for (int t = 0; t < 4; ++t) {
#pragma unroll
            for (int kb = 0; kb < 4; ++kb) {
                int lo = (lane ^ ((kb << 2) | quad)) << 3;
                s16x8 am = *(const s16x8*)(lds_mean + t * 2048 + kb * 512 + lo);
                acc[t] = __builtin_amdgcn_mfma_f32_16x16x32_bf16(am, bl[kb], acc[t], 0, 0, 0);
            }
#pragma unroll
            for (int kb = 0; kb < 4; ++kb) {
                int lo = (lane ^ ((kb << 2) | quad)) << 3;
                s16x8 ah = *(const s16x8*)(lds_hs + t * 2048 + kb * 512 + lo);
                acc[t] = __builtin_amdgcn_mfma_f32_16x16x32_bf16(ah, br[kb], acc[t], 0, 0, 0);
            }
        }
        float bv = bias[bcol];
#pragma unroll
        for (int t = 0; t < 4; ++t) {
#pragma unroll
            for (int r = 0; r < 4; ++r) {
                int orow = row0 + t * 16 + quad * 4 + r;
                float v = fmaxf(acc[t][r] + bv, 0.f);   // relu
                if (WRITE_F32)
                    ((float*)outv)[(size_t)orow * DIM + bcol] = v;
                else
                    ((unsigned short*)outv)[(size_t)orow * DIM + bcol] = f_to_bf16(v);
            }
        }
    }
}

// ---------------- launch ----------------

extern "C" void kernel_launch(void* const* d_in, const int* in_sizes, int n_in,
                              void* d_out, int out_size, void* d_ws, size_t ws_size,
                              hipStream_t stream) {
    const float* x   = (const float*)d_in[0];
    const int*   ei  = (const int*)d_in[1];
    const float* W1l = (const float*)d_in[2];
    const float* b1l = (const float*)d_in[3];
    const float* W1r = (const float*)d_in[4];
    const float* W2l = (const float*)d_in[5];
    const float* b2l = (const float*)d_in[6];
    const float* W2r = (const float*)d_in[7];
    float* out = (float*)d_out;

    const int OUT_ELEMS = NN * DIM;        // 5,120,000

    // workspace layout (256B-aligned)
    const size_t OFF_DEG  = 0;             // N ints
    const size_t OFF_ROW  = 163840;        // N+1 ints
    const size_t OFF_BSUM = 324608;        // NBLK ints (in ROW region slack)
    const size_t OFF_CUR  = 327680;        // N ints
    const size_t OFF_FMT  = 491264;        // 1 int
    const size_t OFF_SRT  = 491520;        // E ints
    const size_t OFF_WB   = 3051520;       // 4 * 16384 bf16
    const size_t OFF_XB   = 3182592;       // N*128 bf16
    const size_t OFF_H1   = 23662592;      // N*128 bf16 (MEAN slot unused)
    const size_t NEEDED   = 33902592;

    if (ws_size < NEEDED) {
        fill_const_f32<<<(OUT_ELEMS + 255) / 256, 256, 0, stream>>>(out, OUT_ELEMS, 50.0f);
        return;
    }

    char* ws = (char*)d_ws;
    int* deg     = (int*)(ws + OFF_DEG);
    int* row_ptr = (int*)(ws + OFF_ROW);
    int* bsum    = (int*)(ws + OFF_BSUM);
    int* cursor  = (int*)(ws + OFF_CUR);
    int* fmtflag = (int*)(ws + OFF_FMT);
    int* sorted  = (int*)(ws + OFF_SRT);
    unsigned short* Wb    = (unsigned short*)(ws + OFF_WB);
    unsigned short* xb    = (unsigned short*)(ws + OFF_XB);
    unsigned short* h1b   = (unsigned short*)(ws + OFF_H1);
    unsigned short* W1lb = Wb;
    unsigned short* W1rb = Wb + 16384;
    unsigned short* W2lb = Wb + 32768;
    unsigned short* W2rb = Wb + 49152;

    // 1: conversions + zero deg + fmt detect
    cvt_all<<<5221, 256, 0, stream>>>(x, xb, W1l, W1r, W2l, W2r, Wb, deg, ei, fmtflag);
    // 2-5: CSR build
    count_deg<<<(NE + 255) / 256, 256, 0, stream>>>(ei, fmtflag, deg);
    block_sums<<<NBLK, 256, 0, stream>>>(deg, bsum);
    scan_block2<<<NBLK, 256, 0, stream>>>(deg, bsum, row_ptr, cursor);
    fill_csr<<<(NE + 255) / 256, 256, 0, stream>>>(ei, fmtflag, cursor, sorted);

    // 6: layer 1 (fused aggregate+GEMM, 8 waves/block)
    sage_layer<false><<<NN / 64, 512, 0, stream>>>(xb, row_ptr, sorted, W1lb, W1rb, b1l, h1b);
    // 7: layer 2 (fused aggregate+GEMM, 8 waves/block)
    sage_layer<true><<<NN / 64, 512, 0, stream>>>(h1b, row_ptr, sorted, W2lb, W2rb, b2l, out);
}